// Round 10
// baseline (1957.179 us; speedup 1.0000x reference)
//
#include <hip/hip_runtime.h>
#include <math.h>

// Problem constants
#define BB 4
#define NN 192
#define DIN 768
#define HD 256
#define HH 512
#define PP 513         // BIAFF+1
#define CLS 10
#define NBIG 5130      // CLS*PP
#define KP 544         // PP padded to 17*32
#define WCO_LD 1051
#define LMAX 192

typedef __attribute__((ext_vector_type(8))) __bf16 bf16x8;
typedef __attribute__((ext_vector_type(4))) float f32x4;
typedef unsigned short u16;
typedef unsigned int u32;
typedef unsigned long long u64;

__device__ __forceinline__ float sigf(float x) { return 1.f / (1.f + expf(-x)); }

__device__ __forceinline__ u16 f2bf(float f) {
    u32 x = __float_as_uint(f);
    u32 r = (x + 0x7FFF + ((x >> 16) & 1)) >> 16;
    return (u16)r;
}
__device__ __forceinline__ float bf2f(u16 h) {
    return __uint_as_float(((u32)h) << 16);
}

// ---------------------------------------------------------------------------
// mega_prep: all weight/input splits + LSTM weight packing in ONE launch.
// pack_w layout (4-block scheme): [dh(4)][wave(8)][frag(32)][lane(64)][e(8)]
// ---------------------------------------------------------------------------
__global__ void mega_prep(const float* __restrict__ word_reps,
                          const float* __restrict__ Wih_f, const float* __restrict__ Wih_b,
                          const float* __restrict__ b_f, const float* __restrict__ b_b,
                          const float* __restrict__ mlp1_w, const float* __restrict__ mlp2_w,
                          const float* __restrict__ head_w, const float* __restrict__ tail_w,
                          const float* __restrict__ mlp1_b, const float* __restrict__ mlp2_b,
                          const float* __restrict__ head_b, const float* __restrict__ tail_b,
                          const float* __restrict__ Whh_f, const float* __restrict__ Whh_b,
                          u16* __restrict__ wrph, u16* __restrict__ wrpl,
                          u16* __restrict__ wihh, u16* __restrict__ wihl, float* __restrict__ bias_ih,
                          u16* __restrict__ mwh, u16* __restrict__ mwl, float* __restrict__ bias_mid,
                          u16* __restrict__ pw)
{
    int i = blockIdx.x * blockDim.x + threadIdx.x;
    if (i < 589824) {
        float v = word_reps[i];
        u16 h = f2bf(v);
        wrph[i] = h; wrpl[i] = f2bf(v - bf2f(h));
        return;
    }
    i -= 589824;
    if (i < 1572864) {
        int n = i / 768, k = i - n * 768;
        float v = (n < 1024) ? Wih_f[(size_t)n * 768 + k] : Wih_b[(size_t)(n - 1024) * 768 + k];
        u16 h = f2bf(v);
        wihh[i] = h; wihl[i] = f2bf(v - bf2f(h));
        return;
    }
    i -= 1572864;
    if (i < 1048576) {
        int n = i >> 9, k = i & 511;
        const float* Ws = (n < 512) ? mlp1_w : (n < 1024) ? mlp2_w : (n < 1536) ? head_w : tail_w;
        float v = Ws[(size_t)(n & 511) * 512 + k];
        u16 h = f2bf(v);
        mwh[i] = h; mwl[i] = f2bf(v - bf2f(h));
        return;
    }
    i -= 1048576;
    if (i < 524288) {
        int f = i;
        int e = f & 7;
        int lane = (f >> 3) & 63;
        int frag = (f >> 9) & 31;
        int wave = (f >> 14) & 7;
        int dh = f >> 17;
        int dir = dh >> 1, half = dh & 1;
        int kt = frag >> 2, t = frag & 3;
        int col = half * 512 + wave * 64 + t * 16 + (lane & 15);
        int u = col >> 2, gt = col & 3;
        int g = gt * 256 + u;
        int k = kt * 32 + (lane >> 4) * 8 + e;
        const float* W = dir ? Whh_b : Whh_f;
        pw[f] = f2bf(W[(size_t)g * 256 + k]);
        return;
    }
    i -= 524288;
    if (i < 2048) {
        bias_ih[i] = (i < 1024) ? b_f[i] : b_b[i - 1024];
        return;
    }
    i -= 2048;
    if (i < 2048) {
        bias_mid[i] = (i < 512) ? mlp1_b[i] : (i < 1024) ? mlp2_b[i - 512]
                    : (i < 1536) ? head_b[i - 1024] : tail_b[i - 1536];
    }
}

// ---------------------------------------------------------------------------
// Generic hi/lo bf16 MFMA GEMM: C[m,n] = act(A[m,:K].B[n,:K] + bias[n])
// act: 0 none, 1 gelu, 2 leaky, 3 per-column (n<1024 gelu else leaky)
// ---------------------------------------------------------------------------
__global__ __launch_bounds__(256)
void gemm_mfma_hl(const u16* __restrict__ Ah, const u16* __restrict__ Al,
                  const u16* __restrict__ Bh, const u16* __restrict__ Bl,
                  const float* __restrict__ bias, float* __restrict__ C,
                  int K, int ldc, int act)
{
    const int lane = threadIdx.x & 63, w = threadIdx.x >> 6;
    const int m0 = blockIdx.y * 64;
    const int n0 = blockIdx.x * 64 + w * 16;
    const int arow = m0 + (lane & 15);
    const int brow = n0 + (lane & 15);
    const int koff = (lane >> 4) * 8;
    f32x4 acc[4] = {};

    for (int k0 = 0; k0 < K; k0 += 32) {
        bf16x8 bh = *(const bf16x8*)(Bh + (size_t)brow * K + k0 + koff);
        bf16x8 bl = *(const bf16x8*)(Bl + (size_t)brow * K + k0 + koff);
#pragma unroll
        for (int mi = 0; mi < 4; ++mi) {
            size_t ao = (size_t)(arow + mi * 16) * K + k0 + koff;
            bf16x8 ah = *(const bf16x8*)(Ah + ao);
            bf16x8 al = *(const bf16x8*)(Al + ao);
            acc[mi] = __builtin_amdgcn_mfma_f32_16x16x32_bf16(ah, bh, acc[mi], 0, 0, 0);
            acc[mi] = __builtin_amdgcn_mfma_f32_16x16x32_bf16(ah, bl, acc[mi], 0, 0, 0);
            acc[mi] = __builtin_amdgcn_mfma_f32_16x16x32_bf16(al, bh, acc[mi], 0, 0, 0);
        }
    }
    const int cn = n0 + (lane & 15);
    const float bv = bias ? bias[cn] : 0.f;
    const int am = (act == 3) ? (cn < 1024 ? 1 : 2) : act;
#pragma unroll
    for (int mi = 0; mi < 4; ++mi)
#pragma unroll
        for (int r = 0; r < 4; ++r) {
            int m = m0 + mi * 16 + (lane >> 4) * 4 + r;
            float v = acc[mi][r] + bv;
            if (am == 1) v = 0.5f * v * (1.f + erff(v * 0.70710678118654752f));
            else if (am == 2) v = v > 0.f ? v : 0.01f * v;
            C[(size_t)m * ldc + cn] = v;
        }
}

// ---------------------------------------------------------------------------
// Biaffine M-GEMM (MFMA hi/lo) -> Mb hi/lo bf16.
// Pad columns j in [513,544) are zeroed HERE (grid-stride, disjoint addresses)
// instead of by memset (round-5 lesson: stale pad bytes as bf16 can be NaN).
// ---------------------------------------------------------------------------
__global__ __launch_bounds__(256)
void biaff_mfma(const u16* __restrict__ Ah, const u16* __restrict__ Al,
                const u16* __restrict__ Wh, const u16* __restrict__ Wl,
                u16* __restrict__ Mh, u16* __restrict__ Ml)
{
    // pad zeroing: 768*10*31 = 238080 elements over 41*12*256 = 125952 threads
    {
        int gtid = (blockIdx.y * 41 + blockIdx.x) * 256 + threadIdx.x;
        for (int p = gtid; p < 238080; p += 125952) {
            int m = p / 310, r2 = p - m * 310;
            int kc = r2 / 31, jj = 513 + (r2 - kc * 31);
            size_t o = (size_t)m * (CLS * KP) + kc * KP + jj;
            Mh[o] = 0; Ml[o] = 0;
        }
    }
    const int lane = threadIdx.x & 63, w = threadIdx.x >> 6;
    const int m0 = blockIdx.y * 64;
    const int n0 = blockIdx.x * 128 + w * 32;
    const int arow = m0 + (lane & 15);
    const int koff = (lane >> 4) * 8;
    f32x4 acc[4][2] = {};

    for (int c = 0; c < 17; ++c) {
        const int k0 = c * 32 + koff;
        bf16x8 bh[2], bl[2];
#pragma unroll
        for (int ni = 0; ni < 2; ++ni) {
            size_t bo = (size_t)(n0 + ni * 16 + (lane & 15)) * KP + k0;
            bh[ni] = *(const bf16x8*)(Wh + bo);
            bl[ni] = *(const bf16x8*)(Wl + bo);
        }
#pragma unroll
        for (int mi = 0; mi < 4; ++mi) {
            size_t ao = (size_t)(arow + mi * 16) * KP + k0;
            bf16x8 ah = *(const bf16x8*)(Ah + ao);
            bf16x8 al = *(const bf16x8*)(Al + ao);
#pragma unroll
            for (int ni = 0; ni < 2; ++ni) {
                acc[mi][ni] = __builtin_amdgcn_mfma_f32_16x16x32_bf16(ah, bh[ni], acc[mi][ni], 0, 0, 0);
                acc[mi][ni] = __builtin_amdgcn_mfma_f32_16x16x32_bf16(ah, bl[ni], acc[mi][ni], 0, 0, 0);
                acc[mi][ni] = __builtin_amdgcn_mfma_f32_16x16x32_bf16(al, bh[ni], acc[mi][ni], 0, 0, 0);
            }
        }
    }
#pragma unroll
    for (int mi = 0; mi < 4; ++mi)
#pragma unroll
        for (int ni = 0; ni < 2; ++ni) {
            int n = n0 + ni * 16 + (lane & 15);
            if (n < NBIG) {
                int kc = n / PP, j = n - kc * PP;
#pragma unroll
                for (int r = 0; r < 4; ++r) {
                    int m = m0 + mi * 16 + (lane >> 4) * 4 + r;
                    float v = acc[mi][ni][r];
                    u16 h = f2bf(v);
                    size_t o = (size_t)m * (CLS * KP) + kc * KP + j;
                    Mh[o] = h; Ml[o] = f2bf(v - bf2f(h));
                }
            }
        }
}

// ---------------------------------------------------------------------------
// Final GEMM (MFMA hi/lo) + epilogue
// ---------------------------------------------------------------------------
__global__ __launch_bounds__(256)
void final_mfma(const u16* __restrict__ Mh, const u16* __restrict__ Ml,
                const u16* __restrict__ Th, const u16* __restrict__ Tl,
                const float* __restrict__ hv, const float* __restrict__ tv,
                const float* __restrict__ Tt, float* __restrict__ out)
{
    const int lane = threadIdx.x & 63, w = threadIdx.x >> 6;
    const int r0 = blockIdx.y * 64;
    const int b = r0 / 1920;
    const int rem = r0 - b * 1920;
    const int kc = rem / 192;
    const int x0 = rem - kc * 192;
    const int n0 = blockIdx.x * 64 + w * 16;
    const int koff = (lane >> 4) * 8;
    const size_t abase = (size_t)(b * 192 + x0 + (lane & 15)) * (CLS * KP) + kc * KP;
    const size_t bbase = (size_t)(b * 192 + n0 + (lane & 15)) * KP;
    f32x4 acc[4] = {};

    for (int c = 0; c < 17; ++c) {
        const int k0 = c * 32 + koff;
        bf16x8 bh = *(const bf16x8*)(Th + bbase + k0);
        bf16x8 bl = *(const bf16x8*)(Tl + bbase + k0);
#pragma unroll
        for (int mi = 0; mi < 4; ++mi) {
            size_t ao = abase + (size_t)mi * 16 * (CLS * KP) + k0;
            bf16x8 ah = *(const bf16x8*)(Mh + ao);
            bf16x8 al = *(const bf16x8*)(Ml + ao);
            acc[mi] = __builtin_amdgcn_mfma_f32_16x16x32_bf16(ah, bh, acc[mi], 0, 0, 0);
            acc[mi] = __builtin_amdgcn_mfma_f32_16x16x32_bf16(ah, bl, acc[mi], 0, 0, 0);
            acc[mi] = __builtin_amdgcn_mfma_f32_16x16x32_bf16(al, bh, acc[mi], 0, 0, 0);
        }
    }
    const int bk = b * 10 + kc;
    const int y = n0 + (lane & 15);
    const float tvv = tv[bk * 192 + y];
#pragma unroll
    for (int mi = 0; mi < 4; ++mi)
#pragma unroll
        for (int r = 0; r < 4; ++r) {
            int x = x0 + mi * 16 + (lane >> 4) * 4 + r;
            int d = y - x;
            d = d < -15 ? -15 : (d > 14 ? 14 : d);
            float v = acc[mi][r] + hv[bk * 192 + x] + tvv + Tt[kc * 30 + d + 15];
            out[(size_t)(bk * 192 + x) * 192 + y] = v;
        }
}

// ---------------------------------------------------------------------------
// Weight-stationary MFMA BiLSTM scan (blocks 0-3) + wsplit (blocks >= 4).
// Scan = r9 body with LOCAL-FIRST reorder: per step, compute the local-half
// MFMA (my h, already in LDS) BEFORE polling the partner's stamped word —
// the polled word was posted one full phase earlier, so the first poll hits.
// Post h(t+1) -> slot (t+1)&1 stamp t+1; poll h(t) <- slot t&1 stamp t.
// Slot reuse safe: my post(t+2) happens only after my import(t+1), which
// requires partner's post(t+1), which happens after partner consumed h(t).
// wsplit: biaffW (10,513,513) -> Wsp[n][k] hi/lo bf16 transpose (2 tiles/blk),
// runs on idle CUs concurrently with the scan (independent data).
// ---------------------------------------------------------------------------
__global__ __launch_bounds__(512, 1)
void lstm_mfma(const float* __restrict__ xw, const u16* __restrict__ pw,
               const int* __restrict__ wl,
               u16* __restrict__ wrsh, u16* __restrict__ wrsl,
               u64* __restrict__ ex,
               const float* __restrict__ biaffW,
               u16* __restrict__ Wsph, u16* __restrict__ Wspl)
{
    if (blockIdx.x >= 4) {
        // ---- wsplit path: two 32x32 tiles per block ----
        __shared__ float tile2[2][32][33];
        const int sub = threadIdx.x >> 8;              // 0..1
        const int tx = threadIdx.x & 31, ty = (threadIdx.x >> 5) & 7;
        const int tt = (blockIdx.x - 4) * 2 + sub;     // 0..2889
        int kc = tt / 289, rem = tt - kc * 289;
        int k0 = (rem % 17) * 32, j0 = (rem / 17) * 32;
#pragma unroll
        for (int yy = 0; yy < 32; yy += 8) {
            int k = k0 + ty + yy, j = j0 + tx;
            tile2[sub][ty + yy][tx] = (k < 513 && j < 513)
                ? biaffW[((size_t)kc * 513 + k) * 513 + j] : 0.f;
        }
        __syncthreads();
#pragma unroll
        for (int yy = 0; yy < 32; yy += 8) {
            int j = j0 + ty + yy, k = k0 + tx;
            if (j < 513 && k < KP) {
                float v = tile2[sub][tx][ty + yy];
                size_t o = ((size_t)kc * 513 + j) * KP + k;
                u16 h = f2bf(v);
                Wsph[o] = h; Wspl[o] = f2bf(v - bf2f(h));
            }
        }
        return;
    }

    // ---- scan path ----
    const int dh = blockIdx.x;            // 0..3
    const int dir = dh >> 1, half = dh & 1;
    const int tid = threadIdx.x;
    const int lane = tid & 63, wid = tid >> 6;

    __shared__ __align__(16) u16 h_hi[16 * 256];
    __shared__ __align__(16) u16 h_lo[16 * 256];
    __shared__ __align__(16) float gates_s[512 * 4];

    for (int i = tid; i < 16 * 256; i += 512) { h_hi[i] = 0; h_lo[i] = 0; }

    // stationary B-frags: 32 x 16B per lane
    bf16x8 bw[32];
    {
        const u16* base = pw + ((size_t)(dh * 8 + wid) * 32 * 64 + lane) * 8;
#pragma unroll
        for (int i = 0; i < 32; ++i)
            bw[i] = *reinterpret_cast<const bf16x8*>(base + (size_t)i * 64 * 8);
    }

    const int u_loc = tid >> 2, bb = tid & 3;
    const int u_glob = half * 128 + u_loc;
    const int Lb = wl[bb];
    float c_state = 0.f, h_state = 0.f;

    const int row = lane & 15, quad = lane >> 4;
    const int abase = row * 512 + quad * 16;
    const int aswz = (row & 7) << 4;
    const int wswz = bb << 4;

    const int kl0 = half * 4;          // local K-subtiles (my half's h)
    const int kr0 = 4 - half * 4;      // remote K-subtiles

    __syncthreads();

    f32x4 acc[4];
    for (int t = 0; t < LMAX; ++t) {
        int ttok = (dir == 0) ? t : (Lb - 1 - t);
        if (ttok < 0) ttok = 0;
        const float* xrow = xw + ((size_t)(bb * 192 + ttok)) * 2048 + dir * 1024 + u_glob;
        float x0 = xrow[0], x1 = xrow[256], x2 = xrow[512], x3 = xrow[768];

        // ---- local-half MFMA (h(t) of my half, written by me last iter) ----
#pragma unroll
        for (int tt = 0; tt < 4; ++tt) acc[tt] = (f32x4){0.f, 0.f, 0.f, 0.f};
#pragma unroll
        for (int k2 = 0; k2 < 4; ++k2) {
            const int kt = kl0 + k2;
            int off = (abase + kt * 64) ^ aswz;
            bf16x8 ah = *reinterpret_cast<const bf16x8*>((const char*)h_hi + off);
            bf16x8 al = *reinterpret_cast<const bf16x8*>((const char*)h_lo + off);
#pragma unroll
            for (int tt = 0; tt < 4; ++tt) {
                acc[tt] = __builtin_amdgcn_mfma_f32_16x16x32_bf16(ah, bw[kt * 4 + tt], acc[tt], 0, 0, 0);
                acc[tt] = __builtin_amdgcn_mfma_f32_16x16x32_bf16(al, bw[kt * 4 + tt], acc[tt], 0, 0, 0);
            }
        }

        // ---- import partner h(t) (posted one phase ago -> poll should hit) ----
        if (t > 0) {
            const u64* pp = &ex[((size_t)(dh ^ 1) * 2 + (t & 1)) * 512 + tid];
            u64 pv;
            do {
                pv = __hip_atomic_load(pp, __ATOMIC_RELAXED, __HIP_MEMORY_SCOPE_AGENT);
                if ((u32)(pv >> 32) == (u32)t) break;
                __builtin_amdgcn_s_sleep(1);
            } while (true);
            u32 pk = (u32)pv;
            int pu = (half ^ 1) * 128 + u_loc;
            int lb2 = (bb * 512 + pu * 2) ^ wswz;
            *(u16*)((char*)h_hi + lb2) = (u16)(pk & 0xFFFFu);
            *(u16*)((char*)h_lo + lb2) = (u16)(pk >> 16);
        }
        __syncthreads();

        // ---- remote-half MFMA ----
#pragma unroll
        for (int k2 = 0; k2 < 4; ++k2) {
            const int kt = kr0 + k2;
            int off = (abase + kt * 64) ^ aswz;
            bf16x8 ah = *reinterpret_cast<const bf16x8*>((const char*)h_hi + off);
            bf16x8 al = *reinterpret_cast<const bf16x8*>((const char*)h_lo + off);
#pragma unroll
            for (int tt = 0; tt < 4; ++tt) {
                acc[tt] = __builtin_amdgcn_mfma_f32_16x16x32_bf16(ah, bw[kt * 4 + tt], acc[tt], 0, 0, 0);
                acc[tt] = __builtin_amdgcn_mfma_f32_16x16x32_bf16(al, bw[kt * 4 + tt], acc[tt], 0, 0, 0);
            }
        }
        if (lane < 16) {
#pragma unroll
            for (int tt = 0; tt < 4; ++tt) {
                int col_loc = wid * 64 + tt * 16 + lane;
                *reinterpret_cast<f32x4*>(&gates_s[col_loc * 4]) = acc[tt];
            }
        }
        __syncthreads();

        // ---- update: one (unit, batch) per thread ----
        float gi = gates_s[(u_loc * 4 + 0) * 4 + bb] + x0;
        float gf = gates_s[(u_loc * 4 + 1) * 4 + bb] + x1;
        float gg = gates_s[(u_loc * 4 + 2) * 4 + bb] + x2;
        float go = gates_s[(u_loc * 4 + 3) * 4 + bb] + x3;
        float cn = sigf(gf) * c_state + sigf(gi) * tanhf(gg);
        float hn = sigf(go) * tanhf(cn);
        if (t < Lb) { c_state = cn; h_state = hn; }
        u16 hi_b = f2bf(h_state);
        u16 lo_b = f2bf(h_state - bf2f(hi_b));

        // post h(t+1): stamp t+1, slot (t+1)&1 (drains during next local MFMA)
        u64 vv = (u64)(((u32)lo_b << 16) | hi_b) | ((u64)(u32)(t + 1) << 32);
        __hip_atomic_store(&ex[((size_t)dh * 2 + ((t + 1) & 1)) * 512 + tid], vv,
                           __ATOMIC_RELAXED, __HIP_MEMORY_SCOPE_AGENT);

        if (t < Lb) {
            size_t wo = ((size_t)(bb * 192 + ttok)) * 512 + dir * 256 + u_glob;
            wrsh[wo] = hi_b; wrsl[wo] = lo_b;
        }
        {
            int lb2 = (bb * 512 + u_glob * 2) ^ wswz;
            *(u16*)((char*)h_hi + lb2) = hi_b;
            *(u16*)((char*)h_lo + lb2) = lo_b;
        }
        __syncthreads();
    }
}

// ---------------------------------------------------------------------------
// post_ht: blocks 0..39 hv/tv, 40..41 Tt, 42+ split_ht (h1/t1 hi/lo + ones)
// ---------------------------------------------------------------------------
__global__ __launch_bounds__(256)
void post_ht(const float* __restrict__ HT, const float* __restrict__ Wco,
             const float* __restrict__ size_emb,
             u16* __restrict__ h1h, u16* __restrict__ h1l,
             u16* __restrict__ t1h, u16* __restrict__ t1l,
             float* __restrict__ hv, float* __restrict__ tv, float* __restrict__ Tt)
{
    int bk = blockIdx.x;
    if (bk < 40) {
        int b = bk / 10, k = bk - (bk / 10) * 10;
        int wave = threadIdx.x >> 6, lane = threadIdx.x & 63;
        const float* wk = Wco + k * WCO_LD;
        for (int x = wave; x < 192; x += 4) {
            const float* hrow = HT + (size_t)(b * 192 + x) * 2048 + 1024;
            float sh = 0.f, st = 0.f;
            for (int i = lane; i < 512; i += 64) {
                sh = fmaf(hrow[i], wk[i], sh);
                st = fmaf(hrow[512 + i], wk[513 + i], st);
            }
#pragma unroll
            for (int o = 32; o; o >>= 1) {
                sh += __shfl_down(sh, o);
                st += __shfl_down(st, o);
            }
            if (lane == 0) {
                hv[bk * 192 + x] = sh + wk[512];
                tv[bk * 192 + x] = st + wk[1025];
            }
        }
    } else if (bk < 42) {
        int idx = (bk - 40) * 256 + threadIdx.x;
        if (idx < 300) {
            int k = idx / 30, p = idx - (idx / 30) * 30;
            float s = 0.f;
            for (int e = 0; e < 25; ++e)
                s = fmaf(size_emb[p * 25 + e], Wco[k * WCO_LD + 1026 + e], s);
            Tt[idx] = s;
        }
    } else {
        int idx = (bk - 42) * 256 + threadIdx.x;
        if (idx < 768 * KP) {
            int m = idx / KP, k = idx - m * KP;
            float hvv = (k < 512) ? HT[(size_t)m * 2048 + k] : (k == 512 ? 1.f : 0.f);
            float tvv = (k < 512) ? HT[(size_t)m * 2048 + 512 + k] : (k == 512 ? 1.f : 0.f);
            u16 hh = f2bf(hvv);
            h1h[idx] = hh; h1l[idx] = f2bf(hvv - bf2f(hh));
            u16 th = f2bf(tvv);
            t1h[idx] = th; t1l[idx] = f2bf(tvv - bf2f(th));
        }
    }
}

extern "C" void kernel_launch(void* const* d_in, const int* in_sizes, int n_in,
                              void* d_out, int out_size, void* d_ws, size_t ws_size,
                              hipStream_t stream)
{
    const float* word_reps = (const float*)d_in[0];
    const int*   word_length = (const int*)d_in[1];
    const float* Wih_f = (const float*)d_in[4];
    const float* Whh_f = (const float*)d_in[5];
    const float* b_f   = (const float*)d_in[6];
    const float* Wih_b = (const float*)d_in[7];
    const float* Whh_b = (const float*)d_in[8];
    const float* b_b   = (const float*)d_in[9];
    const float* mlp1_w = (const float*)d_in[20];
    const float* mlp1_b = (const float*)d_in[21];
    const float* mlp2_w = (const float*)d_in[22];
    const float* mlp2_b = (const float*)d_in[23];
    const float* head_w = (const float*)d_in[24];
    const float* head_b = (const float*)d_in[25];
    const float* tail_w = (const float*)d_in[26];
    const float* tail_b = (const float*)d_in[27];
    const float* biaffW = (const float*)d_in[28];
    const float* size_emb = (const float*)d_in[29];
    const float* W_co = (const float*)d_in[30];

    float* W = (float*)d_ws;
    // region A (dead after mid GEMM; reused by Mbh = [0, 2088960) f32)
    float* xw   = W;                               // [0, 1572864)
    u16*  wrsh  = (u16*)(W + 1572864);             // [1572864, 1769472)
    u16*  wrsl  = (u16*)(W + 1769472);             // [1769472, 1966080)
    u16*  pw    = (u16*)(W + 1966080);             // [1966080, 2228224)
    u16*  Mbh   = (u16*)W;                         // 4,177,920 u16 -> [0, 2088960) f32
    // stable
    float* HT   = W + 2228224;                     // [2228224, 3801088)
    u16* h1h = (u16*)(W + 3801088);
    u16* h1l = (u16*)(W + 4009984);
    u16* t1h = (u16*)(W + 4218880);
    u16* t1l = (u16*)(W + 4427776);
    u16* Wsph = (u16*)(W + 4636672);               // [4636672, 6064128)
    u16* Wspl = (u16*)(W + 6064128);               // [6064128, 7491584)
    u16* Mbl  = (u16*)(W + 7491584);               // [7491584, 9580544)
    //   overlay of Mbl region (dead before biaff): wih split + bias_ih
    u16* wihh = (u16*)(W + 7491584);
    u16* wihl = (u16*)(W + 8278016);
    float* bias_ih = W + 9064448;                  // 2048
    float* hv = W + 9580544;
    float* tv = W + 9588224;
    float* Tt = W + 9595904;                       // 304
    u64* ex   = (u64*)(W + 9596208);               // 4096 u64
    u16* wrph = (u16*)(W + 9604400);               // 589,824 u16
    u16* wrpl = (u16*)(W + 9899312);
    u16* mwh  = (u16*)(W + 10194224);              // 1,048,576 u16
    u16* mwl  = (u16*)(W + 10718512);
    float* bias_mid = W + 11242800;                // 2048
    // high-water ~11,244,848 f32 = 45.0 MB

    // init: wr rows t >= L must be 0; ex stamps must not falsely match (1st call)
    hipMemsetAsync(wrsh, 0, (size_t)393216 * 2 * sizeof(u16), stream);
    hipMemsetAsync(ex, 0, (size_t)4096 * 8, stream);

    mega_prep<<<(3739648 + 255) / 256, 256, 0, stream>>>(
        word_reps, Wih_f, Wih_b, b_f, b_b,
        mlp1_w, mlp2_w, head_w, tail_w, mlp1_b, mlp2_b, head_b, tail_b,
        Whh_f, Whh_b,
        wrph, wrpl, wihh, wihl, bias_ih, mwh, mwl, bias_mid, pw);

    // xw = word_reps @ [Wih_f; Wih_b]^T + bias   (768 x 2048, one launch)
    gemm_mfma_hl<<<dim3(32, 12), 256, 0, stream>>>(wrph, wrpl, wihh, wihl, bias_ih, xw, 768, 2048, 0);

    // BiLSTM scan (blocks 0-3) + biaffW split/transpose (blocks 4-1448, hidden)
    lstm_mfma<<<1449, 512, 0, stream>>>(xw, pw, word_length, wrsh, wrsl, ex,
                                        biaffW, Wsph, Wspl);

    // HT = [gelu(wr@mlp1) | gelu(wr@mlp2) | leaky(wr@head) | leaky(wr@tail)]
    gemm_mfma_hl<<<dim3(32, 12), 256, 0, stream>>>(wrsh, wrsl, mwh, mwl, bias_mid, HT, 512, 2048, 3);

    // hv/tv + Tt + h1/t1 splits in one launch
    post_ht<<<42 + 1632, 256, 0, stream>>>(HT, W_co, size_emb,
                                           h1h, h1l, t1h, t1l, hv, tv, Tt);

    biaff_mfma<<<dim3(41, 12), 256, 0, stream>>>(h1h, h1l, Wsph, Wspl, Mbh, Mbl);
    final_mfma<<<dim3(3, 120), 256, 0, stream>>>(Mbh, Mbl, t1h, t1l, hv, tv, Tt, (float*)d_out);
}